// Round 1
// baseline (678.035 us; speedup 1.0000x reference)
//
#include <hip/hip_runtime.h>
#include <math.h>

// ---------------- problem constants ----------------
#define NPIX 128          // N
#define CCH  768          // channels
#define MASKM 2548        // number of mask positions (static structure)
#define NPAD 2560         // padded GEMM N (20*128)
#define MG   6912         // GEMM M = 9 taps * 768
#define KDIM 768

// ---------------- workspace layout ----------------
static constexpr size_t SZ_H     = (size_t)16384 * 768 * 4;        // h NHWC fp32, 48 MiB
static constexpr size_t OFF_H    = 0;
static constexpr size_t OFF_PART = SZ_H;                           // 128 blocks * 8 doubles
static constexpr size_t OFF_STATS= OFF_PART + 128 * 8 * 8;         // mu[4], rs[4] floats
static constexpr size_t OFF_QI   = OFF_STATS + 256;
static constexpr size_t OFF_QJ   = OFF_QI + 2560 * 4;
static constexpr size_t OFF_SC   = OFF_QJ + 2560 * 4;
static constexpr size_t OFF_X    = OFF_SC + 2560 * 4;              // B matrix [768][2560]
static constexpr size_t OFF_AT   = OFF_X + (size_t)768 * 2560 * 4; // A^T [768][6912]

// ---------------- mask structure (closed form of _build_structure) ----------------
__device__ __forceinline__ bool mask_allowed(int i, int d) {
    if (d == 0) return true;
    if (d <= 15) return true;                                   // stride 1, offsets 1..15
    if (d <= 31) return (d >= 17) && ((d & 1) == 1) && ((i & 1) == 0); // stride 2
    if (d <= 63) return (d >= 35) && ((d & 3) == 3) && ((i & 3) == 0); // stride 4
    return (d >= 71) && ((d & 7) == 7) && ((i & 7) == 0);       // stride 8
}

// qi/qj in row-major np.nonzero order
__global__ void k_struct(int* qi, int* qj) {
    __shared__ int cnt[NPIX], start[NPIX];
    int i = threadIdx.x;
    int c = 0;
    for (int d = 0; i + d < NPIX; ++d) if (mask_allowed(i, d)) ++c;
    cnt[i] = c;
    __syncthreads();
    if (i == 0) { int s = 0; for (int r = 0; r < NPIX; ++r) { start[r] = s; s += cnt[r]; } }
    __syncthreads();
    int base = start[i];
    for (int d = 0; i + d < NPIX; ++d)
        if (mask_allowed(i, d)) { qi[base] = i; qj[base] = i + d; ++base; }
}

// ---------------- X[c][q] = max(fea[c, i..j]) via sparse table ----------------
__global__ void k_buildX(const float* __restrict__ fea, const int* __restrict__ qi,
                         const int* __restrict__ qj, float* __restrict__ X) {
    __shared__ float tab[8][NPIX];
    int c = blockIdx.x, t = threadIdx.x;
    tab[0][t]      = fea[c * NPIX + t];
    tab[0][t + 64] = fea[c * NPIX + t + 64];
    __syncthreads();
    for (int l = 1; l < 8; ++l) {
        int half = 1 << (l - 1), full = 1 << l;
        for (int i = t; i < NPIX; i += 64)
            if (i + full <= NPIX) tab[l][i] = fmaxf(tab[l - 1][i], tab[l - 1][i + half]);
        __syncthreads();
    }
    for (int q = t; q < NPAD; q += 64) {
        float v = 0.f;
        if (q < MASKM) {
            int i = qi[q], j = qj[q];
            int len = j - i + 1;
            int l = 31 - __clz(len);
            v = fmaxf(tab[l][i], tab[l][j + 1 - (1 << l)]);
        }
        X[c * NPAD + q] = v;
    }
}

// ---------------- reorder conv1_w[co][ci][tap] -> At[ci][tap*768+co] ----------------
__global__ void k_reorder(const float* __restrict__ w1, float* __restrict__ At) {
    __shared__ float tile[64][65];
    int co0 = blockIdx.x * 64, cit0 = blockIdx.y * 64;
    int t = threadIdx.x;
    {   // load 64 co rows x 64 (ci*9+tap) cols, coalesced along cit
        int r = t >> 2, cb = (t & 3) << 4;
        const float* src = w1 + (size_t)(co0 + r) * MG + cit0 + cb;
        #pragma unroll
        for (int u = 0; u < 16; u += 4) {
            float4 v = *(const float4*)(src + u);
            tile[r][cb + u]     = v.x;
            tile[r][cb + u + 1] = v.y;
            tile[r][cb + u + 2] = v.z;
            tile[r][cb + u + 3] = v.w;
        }
    }
    __syncthreads();
    // write transposed, coalesced along co (float4 over 16 lanes)
    #pragma unroll
    for (int pass = 0; pass < 4; ++pass) {
        int cc  = (t >> 4) + pass * 16;     // local cit
        int co4 = (t & 15) << 2;            // local co (float4)
        int cit = cit0 + cc;
        int ci = cit / 9, tap = cit % 9;
        float4 v = make_float4(tile[co4][cc], tile[co4 + 1][cc],
                               tile[co4 + 2][cc], tile[co4 + 3][cc]);
        *(float4*)(At + (size_t)ci * MG + tap * 768 + co0 + co4) = v;
    }
}

// ---------------- fp32 GEMM (6912x2560x768) + fused scatter-add into h ----------------
__global__ __launch_bounds__(256) void k_gemm(const float* __restrict__ At,
                                              const float* __restrict__ Bx,
                                              const int* __restrict__ qi,
                                              const int* __restrict__ qj,
                                              float* __restrict__ h) {
    __shared__ float As[16 * 128];
    __shared__ float Bs[16 * 128];
    int tid = threadIdx.x;
    int tx = tid & 15, ty = tid >> 4;
    int m0 = blockIdx.y * 128, n0 = blockIdx.x * 128;

    int ar0 = tid >> 5;                 // rows 0..7
    int ac0 = (tid & 31) << 2;          // col*4
    int ar1 = ar0 + 8;                  // rows 8..15

    float acc[8][8] = {};
    float4 ra0, ra1, rb0, rb1;

    ra0 = *(const float4*)(At + (size_t)ar0 * MG + m0 + ac0);
    ra1 = *(const float4*)(At + (size_t)ar1 * MG + m0 + ac0);
    rb0 = *(const float4*)(Bx + (size_t)ar0 * NPAD + n0 + ac0);
    rb1 = *(const float4*)(Bx + (size_t)ar1 * NPAD + n0 + ac0);

    for (int kb = 0; kb < KDIM / 16; ++kb) {
        __syncthreads();
        *(float4*)&As[ar0 * 128 + ac0] = ra0;
        *(float4*)&As[ar1 * 128 + ac0] = ra1;
        *(float4*)&Bs[ar0 * 128 + ac0] = rb0;
        *(float4*)&Bs[ar1 * 128 + ac0] = rb1;
        __syncthreads();
        if (kb + 1 < KDIM / 16) {
            int k0 = (kb + 1) * 16;
            ra0 = *(const float4*)(At + (size_t)(k0 + ar0) * MG + m0 + ac0);
            ra1 = *(const float4*)(At + (size_t)(k0 + ar1) * MG + m0 + ac0);
            rb0 = *(const float4*)(Bx + (size_t)(k0 + ar0) * NPAD + n0 + ac0);
            rb1 = *(const float4*)(Bx + (size_t)(k0 + ar1) * NPAD + n0 + ac0);
        }
        #pragma unroll
        for (int kk = 0; kk < 16; ++kk) {
            float4 a0 = *(float4*)&As[kk * 128 + (ty << 2)];
            float4 a1 = *(float4*)&As[kk * 128 + (ty << 2) + 64];
            float4 b0 = *(float4*)&Bs[kk * 128 + (tx << 2)];
            float4 b1 = *(float4*)&Bs[kk * 128 + (tx << 2) + 64];
            float a[8] = {a0.x, a0.y, a0.z, a0.w, a1.x, a1.y, a1.z, a1.w};
            float b[8] = {b0.x, b0.y, b0.z, b0.w, b1.x, b1.y, b1.z, b1.w};
            #pragma unroll
            for (int mi = 0; mi < 8; ++mi)
                #pragma unroll
                for (int ni = 0; ni < 8; ++ni)
                    acc[mi][ni] = fmaf(a[mi], b[ni], acc[mi][ni]);
        }
    }

    // scatter: tile lies in a single tap block (768 = 6*128)
    int tap = m0 / 768;
    int dy = tap / 3, dx = tap % 3;
    int coB = (m0 % 768) + (ty << 2);
    #pragma unroll
    for (int ni = 0; ni < 8; ++ni) {
        int q = n0 + (tx << 2) + (ni & 3) + ((ni >> 2) << 6);
        if (q >= MASKM) continue;
        int y = qi[q] + 1 - dy;
        int x = qj[q] + 1 - dx;
        if ((unsigned)y >= 128u || (unsigned)x >= 128u) continue;
        float* hp = h + (size_t)(y * 128 + x) * 768 + coB;
        #pragma unroll
        for (int mi = 0; mi < 8; ++mi) {
            int off = (mi & 3) + ((mi >> 2) << 6);
            unsafeAtomicAdd(hp + off, acc[mi][ni]);
        }
    }
}

// ---------------- GroupNorm stats (double partials, deterministic reduce) ----------------
__global__ void k_stats(const float* __restrict__ h, double* __restrict__ part) {
    int c = threadIdx.x;                       // 768 threads
    int p0 = blockIdx.x * 128;                 // 128 blocks
    double s1 = 0.0, s2 = 0.0;
    for (int pp = 0; pp < 128; ++pp) {
        float v = h[(size_t)(p0 + pp) * 768 + c];
        s1 += v;
        s2 += (double)v * v;
    }
    for (int o = 32; o; o >>= 1) { s1 += __shfl_down(s1, o, 64); s2 += __shfl_down(s2, o, 64); }
    __shared__ double ws1[12], ws2[12];
    int w = c >> 6;
    if ((c & 63) == 0) { ws1[w] = s1; ws2[w] = s2; }
    __syncthreads();
    if (c < 4) {   // group g = 3 waves
        double a = ws1[c * 3] + ws1[c * 3 + 1] + ws1[c * 3 + 2];
        double b = ws2[c * 3] + ws2[c * 3 + 1] + ws2[c * 3 + 2];
        part[blockIdx.x * 8 + c] = a;
        part[blockIdx.x * 8 + 4 + c] = b;
    }
}

__global__ void k_finalize(const double* __restrict__ part, float* __restrict__ stats) {
    int g = threadIdx.x;
    if (g >= 4) return;
    double s1 = 0.0, s2 = 0.0;
    for (int b = 0; b < 128; ++b) { s1 += part[b * 8 + g]; s2 += part[b * 8 + 4 + g]; }
    double cnt = 192.0 * 16384.0;
    double mean = s1 / cnt;
    double var = s2 / cnt - mean * mean;
    stats[g] = (float)mean;
    stats[4 + g] = (float)(1.0 / sqrt(var + 1e-5));
}

// ---------------- fused GN + ReLU + 1x1 conv + sigmoid at mask positions ----------------
__global__ void k_score(const float* __restrict__ h, const float* __restrict__ stats,
                        const float* __restrict__ gamma, const float* __restrict__ beta,
                        const float* __restrict__ w2, const float* __restrict__ b2,
                        const int* __restrict__ qi, const int* __restrict__ qj,
                        float* __restrict__ scores) {
    int q = blockIdx.x * 4 + (threadIdx.x >> 6);
    int lane = threadIdx.x & 63;
    if (q >= MASKM) return;
    const float* hp = h + (size_t)(qi[q] * 128 + qj[q]) * 768;
    float s = 0.f;
    for (int c = lane; c < 768; c += 64) {
        int g = c / 192;
        float v = (hp[c] - stats[g]) * stats[4 + g] * gamma[c] + beta[c];
        s += fmaxf(v, 0.f) * w2[c];
    }
    for (int o = 32; o; o >>= 1) s += __shfl_down(s, o, 64);
    if (lane == 0) scores[q] = 1.f / (1.f + expf(-(s + b2[0])));
}

// ---------------- sort (stable-desc) + greedy NMS + top-5 ----------------
__global__ void k_nms(const float* __restrict__ scores, const int* __restrict__ qi,
                      const int* __restrict__ qj, const int* __restrict__ durp,
                      float* __restrict__ out) {
    __shared__ unsigned long long key[4096];
    __shared__ float ss[MASKM], ee[MASKM];
    __shared__ unsigned char sup[MASKM];
    __shared__ int sh_pick, sh_cnt, sh_cur, sh_keep[5];
    int t = threadIdx.x;

    for (int i = t; i < 4096; i += 1024) {
        unsigned long long k;
        if (i < MASKM) {
            unsigned sb = __float_as_uint(scores[i]);   // scores > 0 -> bits monotonic
            k = ~(((unsigned long long)sb << 32) | (0xFFFFFFFFu - (unsigned)i));
        } else {
            k = 0xFFFFFFFFFFFFFFFFull;                  // pads sink to end
        }
        key[i] = k;
    }
    __syncthreads();
    // bitonic ascending on ~origkey == descending score, ties by ascending q (stable argsort)
    for (int ksz = 2; ksz <= 4096; ksz <<= 1) {
        for (int j = ksz >> 1; j > 0; j >>= 1) {
            for (int i = t; i < 4096; i += 1024) {
                int ixj = i ^ j;
                if (ixj > i) {
                    bool up = ((i & ksz) == 0);
                    unsigned long long a = key[i], b = key[ixj];
                    if ((a > b) == up) { key[i] = b; key[ixj] = a; }
                }
            }
            __syncthreads();
        }
    }
    float delta = (float)(*durp) / 128.f;
    for (int i = t; i < MASKM; i += 1024) {
        unsigned long long k = ~key[i];
        unsigned q = 0xFFFFFFFFu - (unsigned)(k & 0xFFFFFFFFull);
        ss[i] = qi[q] * delta;
        ee[i] = (qj[q] + 1) * delta;
        sup[i] = 0;
    }
    if (t == 0) { sh_cnt = 0; sh_cur = 0; }
    __syncthreads();

    for (int round = 0; round < 5; ++round) {
        if (t == 0) {
            int p = sh_cur;
            while (p < MASKM && sup[p]) ++p;
            if (p < MASKM) { sh_keep[sh_cnt] = p; sh_cnt = sh_cnt + 1; sh_cur = p + 1; sh_pick = p; }
            else sh_pick = -1;
        }
        __syncthreads();
        int pick = sh_pick;
        if (pick < 0) break;
        if (round < 4) {
            float s0 = ss[pick], e0 = ee[pick];
            for (int i2 = pick + 1 + t; i2 < MASKM; i2 += 1024) {
                float inter = fminf(ee[i2], e0) - fmaxf(ss[i2], s0);
                if (inter > 0.f) {
                    float uni = fmaxf(ee[i2], e0) - fminf(ss[i2], s0);
                    if (inter / uni > 0.5f) sup[i2] = 1;
                }
            }
        }
        __syncthreads();
    }
    __syncthreads();
    if (t == 0) {   // fallback: <5 keepers -> top_k ties pick first suppressed (pri==0) in order
        int p = 0;
        while (sh_cnt < 5) {
            while (p < MASKM && !sup[p]) ++p;
            if (p < MASKM) { sh_keep[sh_cnt++] = p; ++p; }
            else { sh_keep[sh_cnt++] = 0; }
        }
    }
    __syncthreads();
    if (t < 5) { out[t * 2] = ss[sh_keep[t]]; out[t * 2 + 1] = ee[sh_keep[t]]; }
}

// ---------------- launch ----------------
extern "C" void kernel_launch(void* const* d_in, const int* in_sizes, int n_in,
                              void* d_out, int out_size, void* d_ws, size_t ws_size,
                              hipStream_t stream) {
    const float* fea   = (const float*)d_in[0];
    const int*   dur   = (const int*)d_in[1];
    const float* w1    = (const float*)d_in[2];
    const float* gamma = (const float*)d_in[3];
    const float* beta  = (const float*)d_in[4];
    const float* w2    = (const float*)d_in[5];
    const float* b2    = (const float*)d_in[6];
    float* out = (float*)d_out;

    char* ws = (char*)d_ws;
    float*  h      = (float*)(ws + OFF_H);
    double* part   = (double*)(ws + OFF_PART);
    float*  stats  = (float*)(ws + OFF_STATS);
    int*    qi     = (int*)(ws + OFF_QI);
    int*    qj     = (int*)(ws + OFF_QJ);
    float*  scores = (float*)(ws + OFF_SC);
    float*  X      = (float*)(ws + OFF_X);
    float*  At     = (float*)(ws + OFF_AT);

    hipMemsetAsync(h, 0, SZ_H, stream);
    k_struct<<<1, 128, 0, stream>>>(qi, qj);
    k_buildX<<<768, 64, 0, stream>>>(fea, qi, qj, X);
    k_reorder<<<dim3(12, 108), 256, 0, stream>>>(w1, At);
    k_gemm<<<dim3(20, 54), 256, 0, stream>>>(At, X, qi, qj, h);
    k_stats<<<128, 768, 0, stream>>>(h, part);
    k_finalize<<<1, 64, 0, stream>>>(part, stats);
    k_score<<<637, 256, 0, stream>>>(h, stats, gamma, beta, w2, b2, qi, qj, scores);
    k_nms<<<1, 1024, 0, stream>>>(scores, qi, qj, dur, out);
}

// Round 2
// 357.806 us; speedup vs baseline: 1.8950x; 1.8950x over previous
//
#include <hip/hip_runtime.h>
#include <math.h>

// ---------------- problem constants ----------------
#define NPIX 128
#define MASKM 2548
#define NPAD 2560          // padded q count (20*128)
#define MG   6912          // GEMM M = 9 taps * 768
#define KD   768

typedef __attribute__((ext_vector_type(8))) short bf16x8;   // 8 bf16 = 4 VGPRs
typedef __attribute__((ext_vector_type(4))) float f32x4;

// ---------------- workspace layout ----------------
static constexpr size_t SZ_QI   = NPAD * 4;
static constexpr size_t SZ_QIDX = 16384 * 4;
static constexpr size_t SZ_PART = 512 * 8 * 8;
static constexpr size_t SZ_STAT = 256;
static constexpr size_t SZ_SC   = NPAD * 4;
static constexpr size_t SZ_HM   = (size_t)MASKM * KD * 4;   // 7.83 MB compact h
static constexpr size_t SZ_AH   = (size_t)MG * KD * 2;      // 10.6 MB bf16
static constexpr size_t SZ_BH   = (size_t)NPAD * KD * 2;    // 3.93 MB bf16
static constexpr size_t SZ_YT   = (size_t)NPAD * MG * 4;    // 70.8 MB fp32

static constexpr size_t OFF_QI   = 0;
static constexpr size_t OFF_QJ   = OFF_QI + SZ_QI;
static constexpr size_t OFF_QIDX = OFF_QJ + SZ_QI;
static constexpr size_t OFF_PART = OFF_QIDX + SZ_QIDX;
static constexpr size_t OFF_STAT = OFF_PART + SZ_PART;
static constexpr size_t OFF_SC   = OFF_STAT + SZ_STAT;
static constexpr size_t OFF_HM   = OFF_SC + SZ_SC;
static constexpr size_t OFF_AH   = OFF_HM + SZ_HM;
static constexpr size_t OFF_AL   = OFF_AH + SZ_AH;
static constexpr size_t OFF_BH   = OFF_AL + SZ_AH;
static constexpr size_t OFF_BL   = OFF_BH + SZ_BH;
static constexpr size_t OFF_YT   = OFF_BL + SZ_BH;
// At (21.2 MB) and X (7.9 MB) alias the Yt region: both dead before Yt is written.
static constexpr size_t OFF_AT   = OFF_YT;
static constexpr size_t OFF_X    = OFF_YT + 22020096;       // 21.2MB rounded up; +7.9 < 70.8 OK
// total ws use: ~103 MiB

// ---------------- bf16 hi/lo split helpers ----------------
__device__ __forceinline__ unsigned short f2bf(float f) {
    unsigned u = __float_as_uint(f);
    u = u + 0x7FFFu + ((u >> 16) & 1u);       // RNE
    return (unsigned short)(u >> 16);
}
__device__ __forceinline__ float bf2f(unsigned short h) {
    return __uint_as_float(((unsigned)h) << 16);
}

// ---------------- mask structure (closed form) ----------------
__device__ __forceinline__ bool mask_allowed(int i, int d) {
    if (d == 0) return true;
    if (d <= 15) return true;
    if (d <= 31) return (d >= 17) && ((d & 1) == 1) && ((i & 1) == 0);
    if (d <= 63) return (d >= 35) && ((d & 3) == 3) && ((i & 3) == 0);
    return (d >= 71) && ((d & 7) == 7) && ((i & 7) == 0);
}

__global__ void k_struct(int* qi, int* qj, int* qidx) {
    __shared__ int cnt[NPIX], start[NPIX];
    int i = threadIdx.x;
    for (int j = 0; j < NPIX; ++j) qidx[i * NPIX + j] = -1;
    int c = 0;
    for (int d = 0; i + d < NPIX; ++d) if (mask_allowed(i, d)) ++c;
    cnt[i] = c;
    __syncthreads();
    if (i == 0) { int s = 0; for (int r = 0; r < NPIX; ++r) { start[r] = s; s += cnt[r]; } }
    __syncthreads();
    int base = start[i];
    for (int d = 0; i + d < NPIX; ++d)
        if (mask_allowed(i, d)) { qi[base] = i; qj[base] = i + d; qidx[i * NPIX + i + d] = base; ++base; }
}

// ---------------- X[c][q] = max(fea[c, i..j]) via sparse table ----------------
__global__ void k_buildX(const float* __restrict__ fea, const int* __restrict__ qi,
                         const int* __restrict__ qj, float* __restrict__ X) {
    __shared__ float tab[8][NPIX];
    int c = blockIdx.x, t = threadIdx.x;
    tab[0][t]      = fea[c * NPIX + t];
    tab[0][t + 64] = fea[c * NPIX + t + 64];
    __syncthreads();
    for (int l = 1; l < 8; ++l) {
        int half = 1 << (l - 1), full = 1 << l;
        for (int i = t; i < NPIX; i += 64)
            if (i + full <= NPIX) tab[l][i] = fmaxf(tab[l - 1][i], tab[l - 1][i + half]);
        __syncthreads();
    }
    for (int q = t; q < NPAD; q += 64) {
        float v = 0.f;
        if (q < MASKM) {
            int i = qi[q], j = qj[q];
            int len = j - i + 1;
            int l = 31 - __clz(len);
            v = fmaxf(tab[l][i], tab[l][j + 1 - (1 << l)]);
        }
        X[c * NPAD + q] = v;
    }
}

// ---------------- reorder conv1_w[co][ci][tap] -> At[ci][tap*768+co] ----------------
__global__ void k_reorder(const float* __restrict__ w1, float* __restrict__ At) {
    __shared__ float tile[64][65];
    int co0 = blockIdx.x * 64, cit0 = blockIdx.y * 64;
    int t = threadIdx.x;
    {
        int r = t >> 2, cb = (t & 3) << 4;
        const float* src = w1 + (size_t)(co0 + r) * MG + cit0 + cb;
        #pragma unroll
        for (int u = 0; u < 16; u += 4) {
            float4 v = *(const float4*)(src + u);
            tile[r][cb + u]     = v.x;
            tile[r][cb + u + 1] = v.y;
            tile[r][cb + u + 2] = v.z;
            tile[r][cb + u + 3] = v.w;
        }
    }
    __syncthreads();
    #pragma unroll
    for (int pass = 0; pass < 4; ++pass) {
        int cc  = (t >> 4) + pass * 16;
        int co4 = (t & 15) << 2;
        int cit = cit0 + cc;
        int ci = cit / 9, tap = cit % 9;
        float4 v = make_float4(tile[co4][cc], tile[co4 + 1][cc],
                               tile[co4 + 2][cc], tile[co4 + 3][cc]);
        *(float4*)(At + (size_t)ci * MG + tap * 768 + co0 + co4) = v;
    }
}

// ---------------- transpose + bf16 hi/lo split: src[768][C] -> dst[C][768] ----------------
__global__ void k_trans(const float* __restrict__ src, int C,
                        unsigned short* __restrict__ dh, unsigned short* __restrict__ dl) {
    __shared__ float tile[64][65];
    int c0 = blockIdx.x * 64, k0 = blockIdx.y * 64;
    int t = threadIdx.x;
    int r = t >> 2, cq = (t & 3) << 4;
    const float* s = src + (size_t)(k0 + r) * C + c0 + cq;
    #pragma unroll
    for (int u = 0; u < 16; u += 4) {
        float4 v = *(const float4*)(s + u);
        tile[r][cq + u]     = v.x;
        tile[r][cq + u + 1] = v.y;
        tile[r][cq + u + 2] = v.z;
        tile[r][cq + u + 3] = v.w;
    }
    __syncthreads();
    size_t ob = (size_t)(c0 + r) * KD + k0 + cq;
    #pragma unroll
    for (int u = 0; u < 16; ++u) {
        float v = tile[cq + u][r];
        unsigned short hi = f2bf(v);
        float lo = v - bf2f(hi);
        dh[ob + u] = hi;
        dl[ob + u] = f2bf(lo);
    }
}

// ---------------- bf16x3 MFMA GEMM: Yt[n][m] = sum_k A[m][k] * B[n][k] ----------------
__global__ __launch_bounds__(256, 2) void k_gemm(const unsigned short* __restrict__ Ah,
                                                 const unsigned short* __restrict__ Al,
                                                 const unsigned short* __restrict__ Bh,
                                                 const unsigned short* __restrict__ Bl,
                                                 float* __restrict__ Yt) {
    __shared__ unsigned short sm[4 * 128 * 32];    // Ah|Al|Bh|Bl tiles, [row][32k], 32 KB
    int tid = threadIdx.x;
    int wave = tid >> 6, lane = tid & 63;
    int m0 = blockIdx.y * 128, n0 = blockIdx.x * 128;
    int wm = (wave & 1) << 6, wn = (wave >> 1) << 6;
    int r4 = lane >> 2, c4 = lane & 3;              // staging: 16 rows x 4 chunks per inst
    int fr = lane & 15, fq = lane >> 4;             // fragment row / quad

    const unsigned short* gsrc[4];
    gsrc[0] = Ah + (size_t)m0 * KD;
    gsrc[1] = Al + (size_t)m0 * KD;
    gsrc[2] = Bh + (size_t)n0 * KD;
    gsrc[3] = Bl + (size_t)n0 * KD;

    f32x4 acc[4][4] = {};

    for (int kb = 0; kb < KD / 32; ++kb) {
        int k0 = kb * 32;
        __syncthreads();
        #pragma unroll
        for (int mat = 0; mat < 4; ++mat) {
            #pragma unroll
            for (int h2 = 0; h2 < 2; ++h2) {
                int rg = wave * 2 + h2;             // 16-row group 0..7
                const unsigned short* g = gsrc[mat] + (size_t)(rg * 16 + r4) * KD + k0 + c4 * 8;
                unsigned short* l = &sm[mat * 4096 + rg * 512];
                __builtin_amdgcn_global_load_lds(
                    (const __attribute__((address_space(1))) unsigned int*)g,
                    (__attribute__((address_space(3))) unsigned int*)l, 16, 0, 0);
            }
        }
        __syncthreads();   // drains vmcnt -> LDS tiles ready
        bf16x8 ah[4], al[4], bh[4], bl[4];
        #pragma unroll
        for (int i = 0; i < 4; ++i) {
            ah[i] = *(const bf16x8*)&sm[0 * 4096 + (wm + i * 16 + fr) * 32 + fq * 8];
            al[i] = *(const bf16x8*)&sm[1 * 4096 + (wm + i * 16 + fr) * 32 + fq * 8];
            bh[i] = *(const bf16x8*)&sm[2 * 4096 + (wn + i * 16 + fr) * 32 + fq * 8];
            bl[i] = *(const bf16x8*)&sm[3 * 4096 + (wn + i * 16 + fr) * 32 + fq * 8];
        }
        #pragma unroll
        for (int mi = 0; mi < 4; ++mi)
            #pragma unroll
            for (int ni = 0; ni < 4; ++ni) {
                acc[mi][ni] = __builtin_amdgcn_mfma_f32_16x16x32_bf16(ah[mi], bh[ni], acc[mi][ni], 0, 0, 0);
                acc[mi][ni] = __builtin_amdgcn_mfma_f32_16x16x32_bf16(ah[mi], bl[ni], acc[mi][ni], 0, 0, 0);
                acc[mi][ni] = __builtin_amdgcn_mfma_f32_16x16x32_bf16(al[mi], bh[ni], acc[mi][ni], 0, 0, 0);
            }
    }
    // epilogue: C/D layout col=lane&15 (n), row=quad*4+reg (m) -> float4 along m into Yt[n][m]
    #pragma unroll
    for (int mi = 0; mi < 4; ++mi)
        #pragma unroll
        for (int ni = 0; ni < 4; ++ni) {
            int n = n0 + wn + ni * 16 + fr;
            int m = m0 + wm + mi * 16 + fq * 4;
            *(f32x4*)(Yt + (size_t)n * MG + m) = acc[mi][ni];
        }
}

// ---------------- gather taps -> h (masked rows only) + GN partial sums ----------------
__global__ __launch_bounds__(256) void k_gather(const float* __restrict__ Yt,
                                                const int* __restrict__ qidx,
                                                float* __restrict__ hm,
                                                double* __restrict__ part) {
    __shared__ double red1[256 * 4], red2[256 * 4];
    int tid = threadIdx.x;
    int wave = tid >> 6, lane = tid & 63;
    double a1[3] = {0, 0, 0}, a2[3] = {0, 0, 0};
    int gs[3];
    #pragma unroll
    for (int s = 0; s < 3; ++s) gs[s] = (64 * s + lane) / 48;   // group of co=s*256+lane*4 (uniform over the 4)

    for (int it = 0; it < 8; ++it) {
        int p = blockIdx.x * 32 + wave * 8 + it;   // pixel, wave-uniform
        int y = p >> 7, x = p & 127;
        float4 hv[3] = {};
        #pragma unroll
        for (int tap = 0; tap < 9; ++tap) {
            int i = y + tap / 3 - 1, j = x + tap % 3 - 1;
            if ((unsigned)i < 128u && (unsigned)j < 128u) {
                int q = qidx[i * NPIX + j];
                if (q >= 0) {
                    const float* yr = Yt + (size_t)q * MG + tap * 768 + lane * 4;
                    #pragma unroll
                    for (int s = 0; s < 3; ++s) {
                        float4 v = *(const float4*)(yr + s * 256);
                        hv[s].x += v.x; hv[s].y += v.y; hv[s].z += v.z; hv[s].w += v.w;
                    }
                }
            }
        }
        int qp = qidx[p];
        if (qp >= 0) {
            #pragma unroll
            for (int s = 0; s < 3; ++s)
                *(float4*)(hm + (size_t)qp * KD + s * 256 + lane * 4) = hv[s];
        }
        #pragma unroll
        for (int s = 0; s < 3; ++s) {
            a1[s] += (double)hv[s].x + (double)hv[s].y + (double)hv[s].z + (double)hv[s].w;
            a2[s] += (double)hv[s].x * hv[s].x + (double)hv[s].y * hv[s].y +
                     (double)hv[s].z * hv[s].z + (double)hv[s].w * hv[s].w;
        }
    }
    #pragma unroll
    for (int g = 0; g < 4; ++g) { red1[tid * 4 + g] = 0.0; red2[tid * 4 + g] = 0.0; }
    #pragma unroll
    for (int s = 0; s < 3; ++s) { red1[tid * 4 + gs[s]] = a1[s]; red2[tid * 4 + gs[s]] = a2[s]; }
    __syncthreads();
    if (tid < 4) {
        double s1 = 0.0, s2 = 0.0;
        for (int i = 0; i < 256; ++i) { s1 += red1[i * 4 + tid]; s2 += red2[i * 4 + tid]; }
        part[blockIdx.x * 8 + tid] = s1;
        part[blockIdx.x * 8 + 4 + tid] = s2;
    }
}

__global__ void k_finalize(const double* __restrict__ part, float* __restrict__ stats) {
    int g = threadIdx.x;
    if (g >= 4) return;
    double s1 = 0.0, s2 = 0.0;
    for (int b = 0; b < 512; ++b) { s1 += part[b * 8 + g]; s2 += part[b * 8 + 4 + g]; }
    double cnt = 192.0 * 16384.0;
    double mean = s1 / cnt;
    double var = s2 / cnt - mean * mean;
    stats[g] = (float)mean;
    stats[4 + g] = (float)(1.0 / sqrt(var + 1e-5));
}

// ---------------- fused GN + ReLU + 1x1 conv + sigmoid at mask positions ----------------
__global__ void k_score(const float* __restrict__ hm, const float* __restrict__ stats,
                        const float* __restrict__ gamma, const float* __restrict__ beta,
                        const float* __restrict__ w2, const float* __restrict__ b2,
                        float* __restrict__ scores) {
    int q = blockIdx.x * 4 + (threadIdx.x >> 6);
    int lane = threadIdx.x & 63;
    if (q >= MASKM) return;
    const float* hp = hm + (size_t)q * KD;
    float s = 0.f;
    for (int c = lane; c < KD; c += 64) {
        int g = c / 192;
        float v = (hp[c] - stats[g]) * stats[4 + g] * gamma[c] + beta[c];
        s += fmaxf(v, 0.f) * w2[c];
    }
    for (int o = 32; o; o >>= 1) s += __shfl_down(s, o, 64);
    if (lane == 0) scores[q] = 1.f / (1.f + expf(-(s + b2[0])));
}

// ---------------- sort (stable-desc) + greedy NMS + top-5 ----------------
__global__ void k_nms(const float* __restrict__ scores, const int* __restrict__ qi,
                      const int* __restrict__ qj, const int* __restrict__ durp,
                      float* __restrict__ out) {
    __shared__ unsigned long long key[4096];
    __shared__ float ss[MASKM], ee[MASKM];
    __shared__ unsigned char sup[MASKM];
    __shared__ int sh_pick, sh_cnt, sh_cur, sh_keep[5];
    int t = threadIdx.x;

    for (int i = t; i < 4096; i += 1024) {
        unsigned long long k;
        if (i < MASKM) {
            unsigned sb = __float_as_uint(scores[i]);
            k = ~(((unsigned long long)sb << 32) | (0xFFFFFFFFu - (unsigned)i));
        } else {
            k = 0xFFFFFFFFFFFFFFFFull;
        }
        key[i] = k;
    }
    __syncthreads();
    for (int ksz = 2; ksz <= 4096; ksz <<= 1) {
        for (int j = ksz >> 1; j > 0; j >>= 1) {
            for (int i = t; i < 4096; i += 1024) {
                int ixj = i ^ j;
                if (ixj > i) {
                    bool up = ((i & ksz) == 0);
                    unsigned long long a = key[i], b = key[ixj];
                    if ((a > b) == up) { key[i] = b; key[ixj] = a; }
                }
            }
            __syncthreads();
        }
    }
    float delta = (float)(*durp) / 128.f;
    for (int i = t; i < MASKM; i += 1024) {
        unsigned long long k = ~key[i];
        unsigned q = 0xFFFFFFFFu - (unsigned)(k & 0xFFFFFFFFull);
        ss[i] = qi[q] * delta;
        ee[i] = (qj[q] + 1) * delta;
        sup[i] = 0;
    }
    if (t == 0) { sh_cnt = 0; sh_cur = 0; }
    __syncthreads();

    for (int round = 0; round < 5; ++round) {
        if (t == 0) {
            int p = sh_cur;
            while (p < MASKM && sup[p]) ++p;
            if (p < MASKM) { sh_keep[sh_cnt] = p; sh_cnt = sh_cnt + 1; sh_cur = p + 1; sh_pick = p; }
            else sh_pick = -1;
        }
        __syncthreads();
        int pick = sh_pick;
        if (pick < 0) break;
        if (round < 4) {
            float s0 = ss[pick], e0 = ee[pick];
            for (int i2 = pick + 1 + t; i2 < MASKM; i2 += 1024) {
                float inter = fminf(ee[i2], e0) - fmaxf(ss[i2], s0);
                if (inter > 0.f) {
                    float uni = fmaxf(ee[i2], e0) - fminf(ss[i2], s0);
                    if (inter / uni > 0.5f) sup[i2] = 1;
                }
            }
        }
        __syncthreads();
    }
    __syncthreads();
    if (t == 0) {
        int p = 0;
        while (sh_cnt < 5) {
            while (p < MASKM && !sup[p]) ++p;
            if (p < MASKM) { sh_keep[sh_cnt++] = p; ++p; }
            else { sh_keep[sh_cnt++] = 0; }
        }
    }
    __syncthreads();
    if (t < 5) { out[t * 2] = ss[sh_keep[t]]; out[t * 2 + 1] = ee[sh_keep[t]]; }
}

// ---------------- launch ----------------
extern "C" void kernel_launch(void* const* d_in, const int* in_sizes, int n_in,
                              void* d_out, int out_size, void* d_ws, size_t ws_size,
                              hipStream_t stream) {
    const float* fea   = (const float*)d_in[0];
    const int*   dur   = (const int*)d_in[1];
    const float* w1    = (const float*)d_in[2];
    const float* gamma = (const float*)d_in[3];
    const float* beta  = (const float*)d_in[4];
    const float* w2    = (const float*)d_in[5];
    const float* b2    = (const float*)d_in[6];
    float* out = (float*)d_out;

    char* ws = (char*)d_ws;
    int*    qi     = (int*)(ws + OFF_QI);
    int*    qj     = (int*)(ws + OFF_QJ);
    int*    qidx   = (int*)(ws + OFF_QIDX);
    double* part   = (double*)(ws + OFF_PART);
    float*  stats  = (float*)(ws + OFF_STAT);
    float*  scores = (float*)(ws + OFF_SC);
    float*  hm     = (float*)(ws + OFF_HM);
    unsigned short* AhU = (unsigned short*)(ws + OFF_AH);
    unsigned short* AlU = (unsigned short*)(ws + OFF_AL);
    unsigned short* BhU = (unsigned short*)(ws + OFF_BH);
    unsigned short* BlU = (unsigned short*)(ws + OFF_BL);
    float*  Yt     = (float*)(ws + OFF_YT);
    float*  At     = (float*)(ws + OFF_AT);   // alias in Yt region
    float*  X      = (float*)(ws + OFF_X);    // alias in Yt region

    k_struct<<<1, 128, 0, stream>>>(qi, qj, qidx);
    k_buildX<<<768, 64, 0, stream>>>(fea, qi, qj, X);
    k_reorder<<<dim3(12, 108), 256, 0, stream>>>(w1, At);
    k_trans<<<dim3(108, 12), 256, 0, stream>>>(At, MG, AhU, AlU);
    k_trans<<<dim3(40, 12), 256, 0, stream>>>(X, NPAD, BhU, BlU);
    k_gemm<<<dim3(20, 54), 256, 0, stream>>>(AhU, AlU, BhU, BlU, Yt);
    k_gather<<<512, 256, 0, stream>>>(Yt, qidx, hm, part);
    k_finalize<<<1, 64, 0, stream>>>(part, stats);
    k_score<<<637, 256, 0, stream>>>(hm, stats, gamma, beta, w2, b2, scores);
    k_nms<<<1, 1024, 0, stream>>>(scores, qi, qj, dur, out);
}